// Round 13
// baseline (35580.585 us; speedup 1.0000x reference)
//
#include <hip/hip_runtime.h>
#include <hip/hip_bf16.h>
#include <stdint.h>

#define T_LEN 1000
#define KIN   69
#define KIN_P 96
#define G3    1536
#define HDIM  512
#define SENT 0xFFFFFFFFu   // bf16 NaN|NaN — unreachable for GRU h in (-1,1)

typedef __attribute__((ext_vector_type(8))) short short8;
typedef __attribute__((ext_vector_type(4))) float f32x4;

#define MFMA(a,b,c) __builtin_amdgcn_mfma_f32_16x16x32_bf16((a),(b),(c),0,0,0)
#define AGENT __HIP_MEMORY_SCOPE_AGENT

static __device__ __forceinline__ float sigm(float x){ return 1.0f/(1.0f+__expf(-x)); }
static __device__ __forceinline__ float tanh_f(float x){
  float a = fabsf(x);
  float e = __expf(2.0f*a);
  float t = 1.0f - 2.0f/(e+1.0f);
  return x >= 0.0f ? t : -t;
}
static __device__ __forceinline__ unsigned short f2bf(float f){
  union { float f; unsigned int u; } v; v.f = f;
  unsigned int u = v.u;
  return (unsigned short)((u + 0x7fffu + ((u>>16)&1u)) >> 16);   // RNE
}

// Poll this thread's 256B h-row portion straight from the LLC. Freshness = no
// dword equals SENT. pmax is a RUNTIME arg: pmax=1 -> "dry" never-wait variant
// (identical machine code; measures body-only time), pmax large -> real wait.
static __device__ __forceinline__ void poll_h(const unsigned long long* h64,
                                              unsigned long long hv[32], int pmax){
  unsigned int ok = 0;
  for (int rounds = 0; ok != 0xFFFFu && rounds < pmax; ++rounds){
    #pragma unroll
    for (int kt=0; kt<16; kt++) if (!(ok & (1u<<kt))){
      hv[2*kt]   = __hip_atomic_load(h64 + kt*8 + 0, __ATOMIC_RELAXED, AGENT);
      hv[2*kt+1] = __hip_atomic_load(h64 + kt*8 + 1, __ATOMIC_RELAXED, AGENT);
    }
    #pragma unroll
    for (int kt=0; kt<16; kt++) if (!(ok & (1u<<kt))){
      unsigned int a = (unsigned int)hv[2*kt],   b = (unsigned int)(hv[2*kt]>>32);
      unsigned int c = (unsigned int)hv[2*kt+1], d = (unsigned int)(hv[2*kt+1]>>32);
      if (a!=SENT && b!=SENT && c!=SENT && d!=SENT) ok |= 1u<<kt;
    }
  }
}

// ---------------- small converters ----------------
__global__ void k_conv(const float* __restrict__ src, unsigned short* __restrict__ dst, int n){
  int i = blockIdx.x*256 + threadIdx.x;
  if (i < n) dst[i] = f2bf(src[i]);
}
__global__ void k_conv_pad(const float* __restrict__ src, unsigned short* __restrict__ dst,
                           int rows, int ks, int kd){
  int i = blockIdx.x*256 + threadIdx.x;
  int r = i / kd, c = i % kd;
  if (r < rows) dst[i] = (c < ks) ? f2bf(src[r*ks + c]) : (unsigned short)0;
}
__global__ void k_sentinel(float* __restrict__ out, int n){
  int i = blockIdx.x*256 + threadIdx.x;
  if (i < n) out[i] = 1234.5f;
}

// x: [64][69][1000] f32  ->  xT: [(t*64+b)][96] bf16
__global__ void k_xpose(const float* __restrict__ x, unsigned short* __restrict__ xT){
  int b = blockIdx.x & 63, tt = blockIdx.x >> 6;
  int t = tt*64 + threadIdx.x;
  if (t >= T_LEN) return;
  unsigned int* dst = (unsigned int*)(xT + (size_t)(t*64+b)*KIN_P);
  #pragma unroll
  for (int i=0;i<48;i++){
    int k0 = 2*i, k1 = 2*i+1;
    unsigned int lo = (k0<KIN) ? f2bf(x[((size_t)b*KIN + k0)*T_LEN + t]) : 0u;
    unsigned int hi = (k1<KIN) ? f2bf(x[((size_t)b*KIN + k1)*T_LEN + t]) : 0u;
    dst[i] = lo | (hi<<16);
  }
}

// ---------------- layer 0: fused input-proj + bidirectional recurrence ----------------
// grid = 32 blocks: dir = bid/16, slice n = bid%16; 3-slot sentinel ring.
#define NB_B 16
__launch_bounds__(512)
__global__ void k_gru0(const unsigned short* __restrict__ xT,
                       const unsigned short* __restrict__ whh0,
                       const unsigned short* __restrict__ wih0,
                       const float* __restrict__ bih_f, const float* __restrict__ bhh_f,
                       const float* __restrict__ bih_b, const float* __restrict__ bhh_b,
                       unsigned short* __restrict__ l0out,
                       unsigned int* __restrict__ hbuf,   // [2][3][64][256] dwords
                       int pmax)
{
  int bid = blockIdx.x;
  int dir = bid / NB_B;
  int n   = bid % NB_B;
  int j0  = n*32;
  int tid = threadIdx.x;
  int w = tid>>6, l = tid&63;
  int m0  = (w & 3) * 16;
  int h16 = w >> 2;
  int lj = l & 15, lg = l >> 4;

  __shared__ unsigned char lds[96*1024 + 96*192];
  unsigned char* whh_lds = lds;
  unsigned char* wih_lds = lds + 96*1024;
  const unsigned short* whh_g = whh0 + (size_t)dir*G3*HDIM;
  const unsigned short* wih_g = wih0 + (size_t)dir*G3*KIN_P;

  for (int c = tid; c < 96*64; c += 512){
    int lr = c >> 6, c16 = c & 63;
    int g = lr >> 5, jl = lr & 31;
    int gr = g*512 + j0 + jl;
    uint4 v = *(const uint4*)(whh_g + (size_t)gr*HDIM + c16*8);
    *(uint4*)(whh_lds + lr*1024 + ((c16*16) ^ ((lr&7)<<4))) = v;
  }
  for (int c = tid; c < 96*12; c += 512){
    int lr = c / 12, c16 = c % 12;
    int g = lr >> 5, jl = lr & 31;
    int gr = g*512 + j0 + jl;
    uint4 v = *(const uint4*)(wih_g + (size_t)gr*KIN_P + c16*8);
    *(uint4*)(wih_lds + lr*192 + ((c16*16) ^ ((lr&3)<<4))) = v;
  }
  __syncthreads();

  int jl_mine = h16*16 + lj;
  int jg = j0 + jl_mine;
  const float* bih = dir ? bih_b : bih_f;
  const float* bhh = dir ? bhh_b : bhh_f;
  float brz = bih[jg] + bhh[jg];
  float bzz = bih[512+jg] + bhh[512+jg];
  float bxn = bih[1024+jg];
  float bhn = bhh[1024+jg];
  float hreg[4] = {0.f,0.f,0.f,0.f};
  unsigned int* hb = hbuf + (size_t)dir*3*64*256;

  for (int ts = 0; ts < T_LEN; ts++){
    int t = dir ? (T_LEN-1-ts) : ts;
    int s_r = ts % 3, s_w = (ts+1) % 3, s_s = (ts+2) % 3;
    f32x4 aR={0.f,0.f,0.f,0.f}, aZ={0.f,0.f,0.f,0.f}, aXN={0.f,0.f,0.f,0.f}, aHN={0.f,0.f,0.f,0.f};

    // input-projection (independent of h)
    const unsigned short* arow = xT + (size_t)(t*64 + m0 + lj)*KIN_P + lg*8;
    #pragma unroll
    for (int kt=0; kt<3; kt++){
      short8 a = *(const short8*)(arow + kt*32);
      int lr0 = jl_mine, lr1 = 32 + jl_mine, lr2 = 64 + jl_mine;
      int co = kt*64 + lg*16;
      short8 b0 = *(const short8*)(wih_lds + lr0*192 + (co ^ ((lr0&3)<<4)));
      short8 b1 = *(const short8*)(wih_lds + lr1*192 + (co ^ ((lr1&3)<<4)));
      short8 b2 = *(const short8*)(wih_lds + lr2*192 + (co ^ ((lr2&3)<<4)));
      aR  = MFMA(a, b0, aR);
      aZ  = MFMA(a, b1, aZ);
      aXN = MFMA(a, b2, aXN);
    }

    // poll h(ts) directly (self-announcing data; ts=0 slot holds zeros = fresh)
    unsigned long long hv[32];
    const unsigned long long* h64 = (const unsigned long long*)(hb + s_r*64*256)
        + ((((m0+lj)*256) + lg*4) >> 1);
    poll_h(h64, hv, pmax);

    #pragma unroll
    for (int kt=0; kt<16; kt++){
      union { unsigned long long u[2]; short8 s; } cv;
      cv.u[0] = hv[2*kt]; cv.u[1] = hv[2*kt+1];
      int lr0 = jl_mine, lr1 = 32 + jl_mine, lr2 = 64 + jl_mine;
      int co = kt*64 + lg*16;
      short8 b0 = *(const short8*)(whh_lds + lr0*1024 + (co ^ ((lr0&7)<<4)));
      short8 b1 = *(const short8*)(whh_lds + lr1*1024 + (co ^ ((lr1&7)<<4)));
      short8 b2 = *(const short8*)(whh_lds + lr2*1024 + (co ^ ((lr2&7)<<4)));
      aR  = MFMA(cv.s, b0, aR);
      aZ  = MFMA(cv.s, b1, aZ);
      aHN = MFMA(cv.s, b2, aHN);
    }

    float hnew[4];
    #pragma unroll
    for (int i=0;i<4;i++){
      float r = sigm(aR[i] + brz);
      float z = sigm(aZ[i] + bzz);
      float nn = tanh_f(aXN[i] + bxn + r*(aHN[i] + bhn));
      hnew[i] = (1.0f - z)*nn + z*hreg[i];
      hreg[i] = hnew[i];
    }

    if (ts < T_LEN-1){
      unsigned int packed[4];
      #pragma unroll
      for (int i=0;i<4;i++){
        unsigned short mybf = f2bf(hnew[i]);
        unsigned short ot = (unsigned short)__shfl_xor((int)mybf, 1, 64);
        packed[i] = (unsigned int)mybf | ((unsigned int)ot << 16);
      }
      if ((l & 1) == 0){
        unsigned int* hs = hb + s_s*64*256;
        unsigned int* hw = hb + s_w*64*256;
        #pragma unroll
        for (int i=0;i<4;i++){
          int b = m0 + lg*4 + i;
          __hip_atomic_store(hs + b*256 + (jg>>1), SENT, __ATOMIC_RELAXED, AGENT);
          __hip_atomic_store(hw + b*256 + (jg>>1), packed[i], __ATOMIC_RELAXED, AGENT);
        }
      }
    }

    #pragma unroll
    for (int i=0;i<4;i++){
      int b = m0 + lg*4 + i;
      l0out[(size_t)(t*64+b)*1024 + dir*512 + jg] = f2bf(hnew[i]);
    }
  }
}

// ---------------- layer 1: fused input-proj + fwd recurrence; bwd is ONE step ----------------
__launch_bounds__(256)
__global__ void k_gru1(const unsigned short* __restrict__ l0out,
                       const unsigned short* __restrict__ wih1,
                       const unsigned short* __restrict__ whh1f,
                       const float* __restrict__ bih_f, const float* __restrict__ bhh_f,
                       const float* __restrict__ bih_b, const float* __restrict__ bhh_b,
                       float* __restrict__ l1cat,
                       unsigned int* __restrict__ hbuf,   // [3][64][256] dwords
                       int pmax)
{
  int bid = blockIdx.x;
  int bwd = bid >= 32;
  int n = bwd ? bid - 32 : bid;
  int j0 = n*16;
  int tid = threadIdx.x;
  int w = tid>>6, l = tid&63;
  int m0 = w*16, lj = l&15, lg = l>>4;

  __shared__ unsigned char lds[48*2048 + 48*1024];
  unsigned char* wih_lds = lds;
  unsigned char* whh_lds = lds + 48*2048;
  const unsigned short* wih_g = wih1 + (bwd ? (size_t)G3*1024 : 0);

  for (int c = tid; c < 48*128; c += 256){
    int lr = c >> 7, c16 = c & 127;
    int g = lr >> 4, jl = lr & 15;
    int gr = g*512 + j0 + jl;
    uint4 v = *(const uint4*)(wih_g + (size_t)gr*1024 + c16*8);
    *(uint4*)(wih_lds + lr*2048 + ((c16*16) ^ ((lr&7)<<4))) = v;
  }
  if (!bwd){
    for (int c = tid; c < 48*64; c += 256){
      int lr = c >> 6, c16 = c & 63;
      int g = lr >> 4, jl = lr & 15;
      int gr = g*512 + j0 + jl;
      uint4 v = *(const uint4*)(whh1f + (size_t)gr*HDIM + c16*8);
      *(uint4*)(whh_lds + lr*1024 + ((c16*16) ^ ((lr&7)<<4))) = v;
    }
  }
  __syncthreads();

  int jg = j0 + lj;
  const float* bih = bwd ? bih_b : bih_f;
  const float* bhh = bwd ? bhh_b : bhh_f;
  float brz = bih[jg] + bhh[jg];
  float bzz = bih[512+jg] + bhh[512+jg];
  float bxn = bih[1024+jg];
  float bhn = bhh[1024+jg];

  if (bwd){
    int t = T_LEN-1;
    f32x4 aR={0.f,0.f,0.f,0.f}, aZ={0.f,0.f,0.f,0.f}, aXN={0.f,0.f,0.f,0.f};
    const unsigned short* arow = l0out + (size_t)(t*64 + m0 + lj)*1024 + lg*8;
    #pragma unroll 8
    for (int kt=0; kt<32; kt++){
      short8 a = *(const short8*)(arow + kt*32);
      int lr0 = lj, lr1 = 16+lj, lr2 = 32+lj;
      int co = kt*64 + lg*16;
      short8 b0 = *(const short8*)(wih_lds + lr0*2048 + (co ^ ((lr0&7)<<4)));
      short8 b1 = *(const short8*)(wih_lds + lr1*2048 + (co ^ ((lr1&7)<<4)));
      short8 b2 = *(const short8*)(wih_lds + lr2*2048 + (co ^ ((lr2&7)<<4)));
      aR = MFMA(a,b0,aR); aZ = MFMA(a,b1,aZ); aXN = MFMA(a,b2,aXN);
    }
    #pragma unroll
    for (int i=0;i<4;i++){
      float r = sigm(aR[i] + brz);
      float z = sigm(aZ[i] + bzz);
      float nn = tanh_f(aXN[i] + bxn + r*bhn);
      l1cat[(size_t)(m0 + lg*4 + i)*1024 + 512 + jg] = (1.0f - z)*nn;
    }
    return;
  }

  float hreg[4] = {0.f,0.f,0.f,0.f};
  for (int ts = 0; ts < T_LEN; ts++){
    int s_r = ts % 3, s_w = (ts+1) % 3, s_s = (ts+2) % 3;
    f32x4 aR={0.f,0.f,0.f,0.f}, aZ={0.f,0.f,0.f,0.f}, aXN={0.f,0.f,0.f,0.f}, aHN={0.f,0.f,0.f,0.f};
    const unsigned short* arow = l0out + (size_t)(ts*64 + m0 + lj)*1024 + lg*8;
    #pragma unroll 8
    for (int kt=0; kt<32; kt++){
      short8 a = *(const short8*)(arow + kt*32);
      int lr0 = lj, lr1 = 16+lj, lr2 = 32+lj;
      int co = kt*64 + lg*16;
      short8 b0 = *(const short8*)(wih_lds + lr0*2048 + (co ^ ((lr0&7)<<4)));
      short8 b1 = *(const short8*)(wih_lds + lr1*2048 + (co ^ ((lr1&7)<<4)));
      short8 b2 = *(const short8*)(wih_lds + lr2*2048 + (co ^ ((lr2&7)<<4)));
      aR = MFMA(a,b0,aR); aZ = MFMA(a,b1,aZ); aXN = MFMA(a,b2,aXN);
    }

    unsigned long long hv[32];
    const unsigned long long* h64 = (const unsigned long long*)(hbuf + s_r*64*256)
        + ((((m0+lj)*256) + lg*4) >> 1);
    poll_h(h64, hv, pmax);

    #pragma unroll
    for (int kt=0; kt<16; kt++){
      union { unsigned long long u[2]; short8 s; } cv;
      cv.u[0] = hv[2*kt]; cv.u[1] = hv[2*kt+1];
      int lr0 = lj, lr1 = 16+lj, lr2 = 32+lj;
      int co = kt*64 + lg*16;
      short8 b0 = *(const short8*)(whh_lds + lr0*1024 + (co ^ ((lr0&7)<<4)));
      short8 b1 = *(const short8*)(whh_lds + lr1*1024 + (co ^ ((lr1&7)<<4)));
      short8 b2 = *(const short8*)(whh_lds + lr2*1024 + (co ^ ((lr2&7)<<4)));
      aR = MFMA(cv.s,b0,aR); aZ = MFMA(cv.s,b1,aZ); aHN = MFMA(cv.s,b2,aHN);
    }
    float hnew[4];
    #pragma unroll
    for (int i=0;i<4;i++){
      float r = sigm(aR[i] + brz);
      float z = sigm(aZ[i] + bzz);
      float nn = tanh_f(aXN[i] + bxn + r*(aHN[i] + bhn));
      hnew[i] = (1.0f - z)*nn + z*hreg[i];
      hreg[i] = hnew[i];
    }
    if (ts < T_LEN-1){
      unsigned int packed[4];
      #pragma unroll
      for (int i=0;i<4;i++){
        unsigned short mybf = f2bf(hnew[i]);
        unsigned short ot = (unsigned short)__shfl_xor((int)mybf, 1, 64);
        packed[i] = (unsigned int)mybf | ((unsigned int)ot << 16);
      }
      if ((l & 1) == 0){
        unsigned int* hs = hbuf + s_s*64*256;
        unsigned int* hw = hbuf + s_w*64*256;
        #pragma unroll
        for (int i=0;i<4;i++){
          int b = m0 + lg*4 + i;
          __hip_atomic_store(hs + b*256 + (jg>>1), SENT, __ATOMIC_RELAXED, AGENT);
          __hip_atomic_store(hw + b*256 + (jg>>1), packed[i], __ATOMIC_RELAXED, AGENT);
        }
      }
    } else {
      #pragma unroll
      for (int i=0;i<4;i++)
        l1cat[(size_t)(m0 + lg*4 + i)*1024 + jg] = hnew[i];
    }
  }
}

// ---------------- final FC ----------------
__global__ void k_fc(const float* __restrict__ l1cat, const float* __restrict__ fcw,
                     const float* __restrict__ fcb, float* __restrict__ out){
  int idx = blockIdx.x*256 + threadIdx.x;
  if (idx >= 64*12) return;
  int b = idx / 12, o = idx % 12;
  float s = fcb[o];
  for (int k=0;k<1024;k++) s += l1cat[b*1024+k]*fcw[o*1024+k];
  out[idx] = s;
}

extern "C" void kernel_launch(void* const* d_in, const int* in_sizes, int n_in,
                              void* d_out, int out_size, void* d_ws, size_t ws_size,
                              hipStream_t stream){
  const float* x     = (const float*)d_in[0];
  const float* wih0f = (const float*)d_in[1];
  const float* whh0f = (const float*)d_in[2];
  const float* bih0f = (const float*)d_in[3];
  const float* bhh0f = (const float*)d_in[4];
  const float* wih0b = (const float*)d_in[5];
  const float* whh0b = (const float*)d_in[6];
  const float* bih0b = (const float*)d_in[7];
  const float* bhh0b = (const float*)d_in[8];
  const float* wih1f = (const float*)d_in[9];
  const float* whh1f = (const float*)d_in[10];
  const float* bih1f = (const float*)d_in[11];
  const float* bhh1f = (const float*)d_in[12];
  const float* wih1b = (const float*)d_in[13];
  const float* bih1b = (const float*)d_in[15];
  const float* bhh1b = (const float*)d_in[16];
  const float* fcw   = (const float*)d_in[17];
  const float* fcb   = (const float*)d_in[18];

  const size_t SLOT = (size_t)64*256*4;   // 64 KB per ring slot

  char* ws = (char*)d_ws;
  size_t off = 0;
  auto alloc = [&](size_t bytes)->void*{ void* p = ws + off; off = (off + bytes + 255) & ~(size_t)255; return p; };
  unsigned short* xT    = (unsigned short*)alloc((size_t)64000*96*2);
  unsigned short* whh0c = (unsigned short*)alloc((size_t)2*1536*512*2);
  unsigned short* wih0c = (unsigned short*)alloc((size_t)2*1536*96*2);
  unsigned short* wih1c = (unsigned short*)alloc((size_t)2*1536*1024*2);
  unsigned short* whh1c = (unsigned short*)alloc((size_t)1536*512*2);
  unsigned short* l0out = (unsigned short*)alloc((size_t)64000*1024*2);
  unsigned int*   hbB   = (unsigned int*)alloc((size_t)2*3*SLOT);   // real ring, layer0
  unsigned int*   hbD   = (unsigned int*)alloc((size_t)3*SLOT);     // real ring, layer1
  unsigned int*   hbX0  = (unsigned int*)alloc((size_t)2*3*SLOT);   // dry scratch ring, layer0
  unsigned int*   hbX1  = (unsigned int*)alloc((size_t)3*SLOT);     // dry scratch ring, layer1
  float*          l1cat = (float*)alloc((size_t)64*1024*4);

  if (off > ws_size){
    k_sentinel<<<(out_size+255)/256,256,0,stream>>>((float*)d_out, out_size);
    return;
  }

  // ring init: slot 0 = zeros (h0 = 0), slots 1..2 = 0xFF sentinel bytes
  for (int d = 0; d < 2; d++){
    char* base = (char*)hbB + (size_t)d*3*SLOT;
    hipMemsetAsync(base, 0, SLOT, stream);
    hipMemsetAsync(base + SLOT, 0xFF, 2*SLOT, stream);
    char* baseX = (char*)hbX0 + (size_t)d*3*SLOT;
    hipMemsetAsync(baseX, 0, SLOT, stream);
    hipMemsetAsync(baseX + SLOT, 0xFF, 2*SLOT, stream);
  }
  hipMemsetAsync(hbD, 0, SLOT, stream);
  hipMemsetAsync((char*)hbD + SLOT, 0xFF, 2*SLOT, stream);
  hipMemsetAsync(hbX1, 0, SLOT, stream);
  hipMemsetAsync((char*)hbX1 + SLOT, 0xFF, 2*SLOT, stream);

  k_conv<<<3072,256,0,stream>>>(whh0f, whh0c, 786432);
  k_conv<<<3072,256,0,stream>>>(whh0b, whh0c+786432, 786432);
  k_conv_pad<<<576,256,0,stream>>>(wih0f, wih0c, 1536, 69, 96);
  k_conv_pad<<<576,256,0,stream>>>(wih0b, wih0c+1536*96, 1536, 69, 96);
  k_conv<<<6144,256,0,stream>>>(wih1f, wih1c, 1572864);
  k_conv<<<6144,256,0,stream>>>(wih1b, wih1c+1572864, 1572864);
  k_conv<<<3072,256,0,stream>>>(whh1f, whh1c, 786432);
  k_xpose<<<1024,64,0,stream>>>(x, xT);

  // DRY gru0 (_ord earlier): pmax=1, scratch ring — body-only time; l0out garbage,
  // fully overwritten by the real run that follows on the same stream.
  k_gru0<<<32,512,0,stream>>>(xT, whh0c, wih0c, bih0f,bhh0f,bih0b,bhh0b, l0out, hbX0, 1);
  // REAL gru0
  k_gru0<<<32,512,0,stream>>>(xT, whh0c, wih0c, bih0f,bhh0f,bih0b,bhh0b, l0out, hbB, 30000);
  // DRY gru1: reads real l0out, writes l1cat garbage (fully overwritten by real).
  k_gru1<<<64,256,0,stream>>>(l0out, wih1c, whh1c, bih1f,bhh1f,bih1b,bhh1b, l1cat, hbX1, 1);
  // REAL gru1
  k_gru1<<<64,256,0,stream>>>(l0out, wih1c, whh1c, bih1f,bhh1f,bih1b,bhh1b, l1cat, hbD, 30000);
  k_fc<<<3,256,0,stream>>>(l1cat, fcw, fcb, (float*)d_out);
}

// Round 14
// 13543.579 us; speedup vs baseline: 2.6271x; 2.6271x over previous
//
#include <hip/hip_runtime.h>
#include <hip/hip_bf16.h>
#include <stdint.h>

#define T_LEN 1000
#define KIN   69
#define KIN_P 96
#define G3    1536
#define HDIM  512
#define SENT 0xFFFFFFFFu   // bf16 NaN|NaN — unreachable for GRU h in (-1,1)

typedef __attribute__((ext_vector_type(8))) short short8;
typedef __attribute__((ext_vector_type(4))) float f32x4;
typedef __attribute__((ext_vector_type(4))) unsigned int u32x4;

#define MFMA(a,b,c) __builtin_amdgcn_mfma_f32_16x16x32_bf16((a),(b),(c),0,0,0)
#define AGENT __HIP_MEMORY_SCOPE_AGENT

// 16B coherent load (bypass L1+L2, served at LLC) / 8B coherent store.
#define LDQ(r, p, o) asm volatile("global_load_dwordx4 %0, %1, off offset:" o " sc0 sc1" : "=v"(r) : "v"(p))
#define STQ(p, v)    asm volatile("global_store_dwordx2 %0, %1, off sc0 sc1" :: "v"(p), "v"(v) : "memory")

static __device__ __forceinline__ float sigm(float x){ return 1.0f/(1.0f+__expf(-x)); }
static __device__ __forceinline__ float tanh_f(float x){
  float a = fabsf(x);
  float e = __expf(2.0f*a);
  float t = 1.0f - 2.0f/(e+1.0f);
  return x >= 0.0f ? t : -t;
}
static __device__ __forceinline__ unsigned short f2bf(float f){
  union { float f; unsigned int u; } v; v.f = f;
  unsigned int u = v.u;
  return (unsigned short)((u + 0x7fffu + ((u>>16)&1u)) >> 16);   // RNE
}

// ---------------- small converters ----------------
__global__ void k_conv(const float* __restrict__ src, unsigned short* __restrict__ dst, int n){
  int i = blockIdx.x*256 + threadIdx.x;
  if (i < n) dst[i] = f2bf(src[i]);
}
__global__ void k_conv_pad(const float* __restrict__ src, unsigned short* __restrict__ dst,
                           int rows, int ks, int kd){
  int i = blockIdx.x*256 + threadIdx.x;
  int r = i / kd, c = i % kd;
  if (r < rows) dst[i] = (c < ks) ? f2bf(src[r*ks + c]) : (unsigned short)0;
}
__global__ void k_sentinel(float* __restrict__ out, int n){
  int i = blockIdx.x*256 + threadIdx.x;
  if (i < n) out[i] = 1234.5f;
}

// x: [64][69][1000] f32  ->  xT: [(t*64+b)][96] bf16
__global__ void k_xpose(const float* __restrict__ x, unsigned short* __restrict__ xT){
  int b = blockIdx.x & 63, tt = blockIdx.x >> 6;
  int t = tt*64 + threadIdx.x;
  if (t >= T_LEN) return;
  unsigned int* dst = (unsigned int*)(xT + (size_t)(t*64+b)*KIN_P);
  #pragma unroll
  for (int i=0;i<48;i++){
    int k0 = 2*i, k1 = 2*i+1;
    unsigned int lo = (k0<KIN) ? f2bf(x[((size_t)b*KIN + k0)*T_LEN + t]) : 0u;
    unsigned int hi = (k1<KIN) ? f2bf(x[((size_t)b*KIN + k1)*T_LEN + t]) : 0u;
    dst[i] = lo | (hi<<16);
  }
}

// ---------------- layer 0: k-split waves, deduped coherent loads ----------------
// grid 32: dir = bid/16, slice n = bid%16 (j-cols [32n,32n+32)).
// Waves: (m-tile w&3, khalf w>>2). Each wave loads h[m-tile][its k-half] ONCE
// (8x16B coherent loads), computes partial gate sums for BOTH j-halves, exchanges
// partials via LDS (2 barriers), finalizes its own j-half (jh = khalf).
#define NB_B 16
__launch_bounds__(512)
__global__ void k_gru0(const unsigned short* __restrict__ xT,
                       const unsigned short* __restrict__ whh0,
                       const unsigned short* __restrict__ wih0,
                       const float* __restrict__ bih_f, const float* __restrict__ bhh_f,
                       const float* __restrict__ bih_b, const float* __restrict__ bhh_b,
                       unsigned short* __restrict__ l0out,
                       unsigned int* __restrict__ hbuf,   // [2][3][64][256] dwords
                       int pmax)
{
  int bid = blockIdx.x;
  int dir = bid / NB_B;
  int n   = bid % NB_B;
  int j0  = n*32;
  int tid = threadIdx.x;
  int w = tid>>6, l = tid&63;
  int m0    = (w & 3) * 16;
  int khalf = w >> 2;          // which k-half this wave loads; also its final j-half
  int lj = l & 15, lg = l >> 4;

  __shared__ unsigned char lds[96*1024 + 96*192 + 32768];
  unsigned char* whh_lds = lds;
  unsigned char* wih_lds = lds + 96*1024;
  f32x4* part4 = (f32x4*)(lds + 96*1024 + 96*192);   // 8 slots x 64 lanes x 4 f32x4 (1 pad)
  const unsigned short* whh_g = whh0 + (size_t)dir*G3*HDIM;
  const unsigned short* wih_g = wih0 + (size_t)dir*G3*KIN_P;

  for (int c = tid; c < 96*64; c += 512){
    int lr = c >> 6, c16 = c & 63;
    int g = lr >> 5, jl = lr & 31;
    int gr = g*512 + j0 + jl;
    uint4 v = *(const uint4*)(whh_g + (size_t)gr*HDIM + c16*8);
    *(uint4*)(whh_lds + lr*1024 + ((c16*16) ^ ((lr&7)<<4))) = v;
  }
  for (int c = tid; c < 96*12; c += 512){
    int lr = c / 12, c16 = c % 12;
    int g = lr >> 5, jl = lr & 31;
    int gr = g*512 + j0 + jl;
    uint4 v = *(const uint4*)(wih_g + (size_t)gr*KIN_P + c16*8);
    *(uint4*)(wih_lds + lr*192 + ((c16*16) ^ ((lr&3)<<4))) = v;
  }
  __syncthreads();

  int jg = j0 + khalf*16 + lj;       // the gate col this lane finalizes
  const float* bih = dir ? bih_b : bih_f;
  const float* bhh = dir ? bhh_b : bhh_f;
  float brz = bih[jg] + bhh[jg];
  float bzz = bih[512+jg] + bhh[512+jg];
  float bxn = bih[1024+jg];
  float bhn = bhh[1024+jg];
  float hreg[4] = {0.f,0.f,0.f,0.f};
  unsigned int* hb = hbuf + (size_t)dir*3*64*256;
  int wslot = (w&3)*2 + khalf;       // my write slot (holds my other-jh partials)
  int rslot = (w&3)*2 + (1-khalf);   // partner's slot (holds my jh partials)

  for (int ts = 0; ts < T_LEN; ts++){
    int t = dir ? (T_LEN-1-ts) : ts;
    int s_r = ts % 3, s_w = (ts+1) % 3, s_s = (ts+2) % 3;

    // ---- input projection for my j-half (independent of h) ----
    f32x4 xR={0.f,0.f,0.f,0.f}, xZ={0.f,0.f,0.f,0.f}, xXN={0.f,0.f,0.f,0.f};
    const unsigned short* arow = xT + (size_t)(t*64 + m0 + lj)*KIN_P + lg*8;
    #pragma unroll
    for (int kt=0; kt<3; kt++){
      short8 a = *(const short8*)(arow + kt*32);
      int r0 = khalf*16 + lj, r1 = 32 + khalf*16 + lj, r2 = 64 + khalf*16 + lj;
      int co = kt*64 + lg*16;
      short8 b0 = *(const short8*)(wih_lds + r0*192 + (co ^ ((r0&3)<<4)));
      short8 b1 = *(const short8*)(wih_lds + r1*192 + (co ^ ((r1&3)<<4)));
      short8 b2 = *(const short8*)(wih_lds + r2*192 + (co ^ ((r2&3)<<4)));
      xR  = MFMA(a, b0, xR);
      xZ  = MFMA(a, b1, xZ);
      xXN = MFMA(a, b2, xXN);
    }

    // ---- poll + load my k-half of h(ts): 8 x 16B coherent loads ----
    u32x4 q0,q1,q2,q3,q4,q5,q6,q7;
    {
      const unsigned char* hbase = (const unsigned char*)(hb + s_r*64*256)
          + (size_t)(m0+lj)*1024 + (size_t)khalf*512 + lg*16;
      unsigned int ok = 0;
      for (int rounds = 0; ok != 0xFFu && rounds < pmax; ++rounds){
        if(!(ok&0x01)) LDQ(q0, hbase, "0");
        if(!(ok&0x02)) LDQ(q1, hbase, "64");
        if(!(ok&0x04)) LDQ(q2, hbase, "128");
        if(!(ok&0x08)) LDQ(q3, hbase, "192");
        if(!(ok&0x10)) LDQ(q4, hbase, "256");
        if(!(ok&0x20)) LDQ(q5, hbase, "320");
        if(!(ok&0x40)) LDQ(q6, hbase, "384");
        if(!(ok&0x80)) LDQ(q7, hbase, "448");
        asm volatile("s_waitcnt vmcnt(0)" ::: "memory");
        __builtin_amdgcn_sched_barrier(0);
        #define CHK0(qq,bit) if(!(ok&bit) && qq[0]!=SENT && qq[1]!=SENT && qq[2]!=SENT && qq[3]!=SENT) ok|=bit
        CHK0(q0,0x01); CHK0(q1,0x02); CHK0(q2,0x04); CHK0(q3,0x08);
        CHK0(q4,0x10); CHK0(q5,0x20); CHK0(q6,0x40); CHK0(q7,0x80);
      }
    }

    // ---- recurrent partial sums over my k-half, BOTH j-halves ----
    f32x4 pR0={0.f,0.f,0.f,0.f}, pZ0={0.f,0.f,0.f,0.f}, pN0={0.f,0.f,0.f,0.f};
    f32x4 pR1={0.f,0.f,0.f,0.f}, pZ1={0.f,0.f,0.f,0.f}, pN1={0.f,0.f,0.f,0.f};
    #define RSTEP(qq, c) { \
      union { u32x4 u; short8 s; } cv; cv.u = qq; \
      int co = (khalf*8 + (c))*64 + lg*16; \
      { int r = lj;      short8 B = *(const short8*)(whh_lds + r*1024 + (co ^ ((r&7)<<4))); pR0 = MFMA(cv.s, B, pR0); } \
      { int r = 16+lj;   short8 B = *(const short8*)(whh_lds + r*1024 + (co ^ ((r&7)<<4))); pR1 = MFMA(cv.s, B, pR1); } \
      { int r = 32+lj;   short8 B = *(const short8*)(whh_lds + r*1024 + (co ^ ((r&7)<<4))); pZ0 = MFMA(cv.s, B, pZ0); } \
      { int r = 48+lj;   short8 B = *(const short8*)(whh_lds + r*1024 + (co ^ ((r&7)<<4))); pZ1 = MFMA(cv.s, B, pZ1); } \
      { int r = 64+lj;   short8 B = *(const short8*)(whh_lds + r*1024 + (co ^ ((r&7)<<4))); pN0 = MFMA(cv.s, B, pN0); } \
      { int r = 80+lj;   short8 B = *(const short8*)(whh_lds + r*1024 + (co ^ ((r&7)<<4))); pN1 = MFMA(cv.s, B, pN1); } \
    }
    RSTEP(q0,0); RSTEP(q1,1); RSTEP(q2,2); RSTEP(q3,3);
    RSTEP(q4,4); RSTEP(q5,5); RSTEP(q6,6); RSTEP(q7,7);

    // ---- exchange: send my other-jh partials, receive my jh from partner ----
    {
      f32x4* wp = part4 + ((size_t)wslot*64 + l)*4;
      if (khalf == 0){ wp[0]=pR1; wp[1]=pZ1; wp[2]=pN1; }
      else           { wp[0]=pR0; wp[1]=pZ0; wp[2]=pN0; }
    }
    __syncthreads();     // partials visible; also: whole block has confirmed all 16 producers
    f32x4 sR, sZ, sN;
    {
      f32x4* rp = part4 + ((size_t)rslot*64 + l)*4;
      if (khalf == 0){ sR = pR0 + rp[0]; sZ = pZ0 + rp[1]; sN = pN0 + rp[2]; }
      else           { sR = pR1 + rp[0]; sZ = pZ1 + rp[1]; sN = pN1 + rp[2]; }
    }
    __syncthreads();     // protect part buffer before next step's writes

    // ---- gates ----
    float hnew[4];
    #pragma unroll
    for (int i=0;i<4;i++){
      float r = sigm(xR[i] + sR[i] + brz);
      float z = sigm(xZ[i] + sZ[i] + bzz);
      float nn = tanh_f(xXN[i] + bxn + r*(sN[i] + bhn));
      hnew[i] = (1.0f - z)*nn + z*hreg[i];
      hreg[i] = hnew[i];
    }

    // ---- arm + publish: 8B packed coherent stores on quarter lanes ----
    if (ts < T_LEN-1){
      unsigned int packed[4];
      unsigned long long pk[4];
      #pragma unroll
      for (int i=0;i<4;i++){
        unsigned short mybf = f2bf(hnew[i]);
        unsigned short ot = (unsigned short)__shfl_xor((int)mybf, 1, 64);
        packed[i] = (unsigned int)mybf | ((unsigned int)ot << 16);
      }
      #pragma unroll
      for (int i=0;i<4;i++){
        unsigned int nb = (unsigned int)__shfl_down((int)packed[i], 2, 64);
        pk[i] = (unsigned long long)packed[i] | ((unsigned long long)nb << 32);
      }
      if ((l & 3) == 0){
        unsigned long long* hs = (unsigned long long*)(hb + s_s*64*256);
        unsigned long long* hw = (unsigned long long*)(hb + s_w*64*256);
        #pragma unroll
        for (int i=0;i<4;i++){
          int b = m0 + lg*4 + i;
          size_t qi = ((size_t)b*256 + (jg>>1)) >> 1;
          STQ(hs + qi, 0xFFFFFFFFFFFFFFFFull);   // arm slot ts+2 first
          STQ(hw + qi, pk[i]);                   // then publish h(ts+1)
        }
      }
    }

    #pragma unroll
    for (int i=0;i<4;i++){
      int b = m0 + lg*4 + i;
      l0out[(size_t)(t*64+b)*1024 + dir*512 + jg] = f2bf(hnew[i]);
    }
  }
}

// ---------------- layer 1: fused input-proj + fwd recurrence; bwd is ONE step ----------------
__launch_bounds__(256)
__global__ void k_gru1(const unsigned short* __restrict__ l0out,
                       const unsigned short* __restrict__ wih1,
                       const unsigned short* __restrict__ whh1f,
                       const float* __restrict__ bih_f, const float* __restrict__ bhh_f,
                       const float* __restrict__ bih_b, const float* __restrict__ bhh_b,
                       float* __restrict__ l1cat,
                       unsigned int* __restrict__ hbuf,   // [3][64][256] dwords
                       int pmax)
{
  int bid = blockIdx.x;
  int bwd = bid >= 32;
  int n = bwd ? bid - 32 : bid;
  int j0 = n*16;
  int tid = threadIdx.x;
  int w = tid>>6, l = tid&63;
  int m0 = w*16, lj = l&15, lg = l>>4;

  __shared__ unsigned char lds[48*2048 + 48*1024];
  unsigned char* wih_lds = lds;
  unsigned char* whh_lds = lds + 48*2048;
  const unsigned short* wih_g = wih1 + (bwd ? (size_t)G3*1024 : 0);

  for (int c = tid; c < 48*128; c += 256){
    int lr = c >> 7, c16 = c & 127;
    int g = lr >> 4, jl = lr & 15;
    int gr = g*512 + j0 + jl;
    uint4 v = *(const uint4*)(wih_g + (size_t)gr*1024 + c16*8);
    *(uint4*)(wih_lds + lr*2048 + ((c16*16) ^ ((lr&7)<<4))) = v;
  }
  if (!bwd){
    for (int c = tid; c < 48*64; c += 256){
      int lr = c >> 6, c16 = c & 63;
      int g = lr >> 4, jl = lr & 15;
      int gr = g*512 + j0 + jl;
      uint4 v = *(const uint4*)(whh1f + (size_t)gr*HDIM + c16*8);
      *(uint4*)(whh_lds + lr*1024 + ((c16*16) ^ ((lr&7)<<4))) = v;
    }
  }
  __syncthreads();

  int jg = j0 + lj;
  const float* bih = bwd ? bih_b : bih_f;
  const float* bhh = bwd ? bhh_b : bhh_f;
  float brz = bih[jg] + bhh[jg];
  float bzz = bih[512+jg] + bhh[512+jg];
  float bxn = bih[1024+jg];
  float bhn = bhh[1024+jg];

  if (bwd){
    int t = T_LEN-1;
    f32x4 aR={0.f,0.f,0.f,0.f}, aZ={0.f,0.f,0.f,0.f}, aXN={0.f,0.f,0.f,0.f};
    const unsigned short* arow = l0out + (size_t)(t*64 + m0 + lj)*1024 + lg*8;
    #pragma unroll 8
    for (int kt=0; kt<32; kt++){
      short8 a = *(const short8*)(arow + kt*32);
      int r0 = lj, r1 = 16+lj, r2 = 32+lj;
      int co = kt*64 + lg*16;
      short8 b0 = *(const short8*)(wih_lds + r0*2048 + (co ^ ((r0&7)<<4)));
      short8 b1 = *(const short8*)(wih_lds + r1*2048 + (co ^ ((r1&7)<<4)));
      short8 b2 = *(const short8*)(wih_lds + r2*2048 + (co ^ ((r2&7)<<4)));
      aR = MFMA(a,b0,aR); aZ = MFMA(a,b1,aZ); aXN = MFMA(a,b2,aXN);
    }
    #pragma unroll
    for (int i=0;i<4;i++){
      float r = sigm(aR[i] + brz);
      float z = sigm(aZ[i] + bzz);
      float nn = tanh_f(aXN[i] + bxn + r*bhn);
      l1cat[(size_t)(m0 + lg*4 + i)*1024 + 512 + jg] = (1.0f - z)*nn;
    }
    return;
  }

  float hreg[4] = {0.f,0.f,0.f,0.f};
  for (int ts = 0; ts < T_LEN; ts++){
    int s_r = ts % 3, s_w = (ts+1) % 3, s_s = (ts+2) % 3;
    f32x4 aR={0.f,0.f,0.f,0.f}, aZ={0.f,0.f,0.f,0.f}, aXN={0.f,0.f,0.f,0.f}, aHN={0.f,0.f,0.f,0.f};
    const unsigned short* arow = l0out + (size_t)(ts*64 + m0 + lj)*1024 + lg*8;
    #pragma unroll 8
    for (int kt=0; kt<32; kt++){
      short8 a = *(const short8*)(arow + kt*32);
      int r0 = lj, r1 = 16+lj, r2 = 32+lj;
      int co = kt*64 + lg*16;
      short8 b0 = *(const short8*)(wih_lds + r0*2048 + (co ^ ((r0&7)<<4)));
      short8 b1 = *(const short8*)(wih_lds + r1*2048 + (co ^ ((r1&7)<<4)));
      short8 b2 = *(const short8*)(wih_lds + r2*2048 + (co ^ ((r2&7)<<4)));
      aR = MFMA(a,b0,aR); aZ = MFMA(a,b1,aZ); aXN = MFMA(a,b2,aXN);
    }

    // ---- poll + load full h(ts): 16 x 16B coherent loads ----
    u32x4 q0,q1,q2,q3,q4,q5,q6,q7,q8,q9,q10,q11,q12,q13,q14,q15;
    {
      const unsigned char* hbase = (const unsigned char*)(hbuf + s_r*64*256)
          + (size_t)(m0+lj)*1024 + lg*16;
      unsigned int ok = 0;
      for (int rounds = 0; ok != 0xFFFFu && rounds < pmax; ++rounds){
        if(!(ok&0x0001)) LDQ(q0, hbase, "0");
        if(!(ok&0x0002)) LDQ(q1, hbase, "64");
        if(!(ok&0x0004)) LDQ(q2, hbase, "128");
        if(!(ok&0x0008)) LDQ(q3, hbase, "192");
        if(!(ok&0x0010)) LDQ(q4, hbase, "256");
        if(!(ok&0x0020)) LDQ(q5, hbase, "320");
        if(!(ok&0x0040)) LDQ(q6, hbase, "384");
        if(!(ok&0x0080)) LDQ(q7, hbase, "448");
        if(!(ok&0x0100)) LDQ(q8, hbase, "512");
        if(!(ok&0x0200)) LDQ(q9, hbase, "576");
        if(!(ok&0x0400)) LDQ(q10, hbase, "640");
        if(!(ok&0x0800)) LDQ(q11, hbase, "704");
        if(!(ok&0x1000)) LDQ(q12, hbase, "768");
        if(!(ok&0x2000)) LDQ(q13, hbase, "832");
        if(!(ok&0x4000)) LDQ(q14, hbase, "896");
        if(!(ok&0x8000)) LDQ(q15, hbase, "960");
        asm volatile("s_waitcnt vmcnt(0)" ::: "memory");
        __builtin_amdgcn_sched_barrier(0);
        #define CHK1(qq,bit) if(!(ok&bit) && qq[0]!=SENT && qq[1]!=SENT && qq[2]!=SENT && qq[3]!=SENT) ok|=bit
        CHK1(q0,0x0001); CHK1(q1,0x0002); CHK1(q2,0x0004); CHK1(q3,0x0008);
        CHK1(q4,0x0010); CHK1(q5,0x0020); CHK1(q6,0x0040); CHK1(q7,0x0080);
        CHK1(q8,0x0100); CHK1(q9,0x0200); CHK1(q10,0x0400); CHK1(q11,0x0800);
        CHK1(q12,0x1000); CHK1(q13,0x2000); CHK1(q14,0x4000); CHK1(q15,0x8000);
      }
    }

    #define RSTEP1(qq, kt) { \
      union { u32x4 u; short8 s; } cv; cv.u = qq; \
      int co = (kt)*64 + lg*16; \
      { int r = lj;    short8 B = *(const short8*)(whh_lds + r*1024 + (co ^ ((r&7)<<4))); aR = MFMA(cv.s, B, aR); } \
      { int r = 16+lj; short8 B = *(const short8*)(whh_lds + r*1024 + (co ^ ((r&7)<<4))); aZ = MFMA(cv.s, B, aZ); } \
      { int r = 32+lj; short8 B = *(const short8*)(whh_lds + r*1024 + (co ^ ((r&7)<<4))); aHN = MFMA(cv.s, B, aHN); } \
    }
    RSTEP1(q0,0); RSTEP1(q1,1); RSTEP1(q2,2); RSTEP1(q3,3);
    RSTEP1(q4,4); RSTEP1(q5,5); RSTEP1(q6,6); RSTEP1(q7,7);
    RSTEP1(q8,8); RSTEP1(q9,9); RSTEP1(q10,10); RSTEP1(q11,11);
    RSTEP1(q12,12); RSTEP1(q13,13); RSTEP1(q14,14); RSTEP1(q15,15);

    float hnew[4];
    #pragma unroll
    for (int i=0;i<4;i++){
      float r = sigm(aR[i] + brz);
      float z = sigm(aZ[i] + bzz);
      float nn = tanh_f(aXN[i] + bxn + r*(aHN[i] + bhn));
      hnew[i] = (1.0f - z)*nn + z*hreg[i];
      hreg[i] = hnew[i];
    }
    if (ts < T_LEN-1){
      unsigned int packed[4];
      unsigned long long pk[4];
      #pragma unroll
      for (int i=0;i<4;i++){
        unsigned short mybf = f2bf(hnew[i]);
        unsigned short ot = (unsigned short)__shfl_xor((int)mybf, 1, 64);
        packed[i] = (unsigned int)mybf | ((unsigned int)ot << 16);
      }
      #pragma unroll
      for (int i=0;i<4;i++){
        unsigned int nb = (unsigned int)__shfl_down((int)packed[i], 2, 64);
        pk[i] = (unsigned long long)packed[i] | ((unsigned long long)nb << 32);
      }
      if ((l & 3) == 0){
        unsigned long long* hs = (unsigned long long*)(hbuf + s_s*64*256);
        unsigned long long* hw = (unsigned long long*)(hbuf + s_w*64*256);
        #pragma unroll
        for (int i=0;i<4;i++){
          int b = m0 + lg*4 + i;
          size_t qi = ((size_t)b*256 + (jg>>1)) >> 1;
          STQ(hs + qi, 0xFFFFFFFFFFFFFFFFull);
          STQ(hw + qi, pk[i]);
        }
      }
    } else {
      #pragma unroll
      for (int i=0;i<4;i++)
        l1cat[(size_t)(m0 + lg*4 + i)*1024 + jg] = hnew[i];
    }
  }
}

// ---------------- final FC ----------------
__global__ void k_fc(const float* __restrict__ l1cat, const float* __restrict__ fcw,
                     const float* __restrict__ fcb, float* __restrict__ out){
  int idx = blockIdx.x*256 + threadIdx.x;
  if (idx >= 64*12) return;
  int b = idx / 12, o = idx % 12;
  float s = fcb[o];
  for (int k=0;k<1024;k++) s += l1cat[b*1024+k]*fcw[o*1024+k];
  out[idx] = s;
}

extern "C" void kernel_launch(void* const* d_in, const int* in_sizes, int n_in,
                              void* d_out, int out_size, void* d_ws, size_t ws_size,
                              hipStream_t stream){
  const float* x     = (const float*)d_in[0];
  const float* wih0f = (const float*)d_in[1];
  const float* whh0f = (const float*)d_in[2];
  const float* bih0f = (const float*)d_in[3];
  const float* bhh0f = (const float*)d_in[4];
  const float* wih0b = (const float*)d_in[5];
  const float* whh0b = (const float*)d_in[6];
  const float* bih0b = (const float*)d_in[7];
  const float* bhh0b = (const float*)d_in[8];
  const float* wih1f = (const float*)d_in[9];
  const float* whh1f = (const float*)d_in[10];
  const float* bih1f = (const float*)d_in[11];
  const float* bhh1f = (const float*)d_in[12];
  const float* wih1b = (const float*)d_in[13];
  const float* bih1b = (const float*)d_in[15];
  const float* bhh1b = (const float*)d_in[16];
  const float* fcw   = (const float*)d_in[17];
  const float* fcb   = (const float*)d_in[18];

  const size_t SLOT = (size_t)64*256*4;   // 64 KB per ring slot

  char* ws = (char*)d_ws;
  size_t off = 0;
  auto alloc = [&](size_t bytes)->void*{ void* p = ws + off; off = (off + bytes + 255) & ~(size_t)255; return p; };
  unsigned short* xT    = (unsigned short*)alloc((size_t)64000*96*2);
  unsigned short* whh0c = (unsigned short*)alloc((size_t)2*1536*512*2);
  unsigned short* wih0c = (unsigned short*)alloc((size_t)2*1536*96*2);
  unsigned short* wih1c = (unsigned short*)alloc((size_t)2*1536*1024*2);
  unsigned short* whh1c = (unsigned short*)alloc((size_t)1536*512*2);
  unsigned short* l0out = (unsigned short*)alloc((size_t)64000*1024*2);
  unsigned int*   hbB   = (unsigned int*)alloc((size_t)2*3*SLOT);   // [2][3][64][256]
  unsigned int*   hbD   = (unsigned int*)alloc((size_t)3*SLOT);     // [3][64][256]
  float*          l1cat = (float*)alloc((size_t)64*1024*4);

  if (off > ws_size){
    k_sentinel<<<(out_size+255)/256,256,0,stream>>>((float*)d_out, out_size);
    return;
  }

  // ring init: slot 0 = zeros (h0 = 0), slots 1..2 = 0xFF sentinel bytes
  for (int d = 0; d < 2; d++){
    char* base = (char*)hbB + (size_t)d*3*SLOT;
    hipMemsetAsync(base, 0, SLOT, stream);
    hipMemsetAsync(base + SLOT, 0xFF, 2*SLOT, stream);
  }
  hipMemsetAsync(hbD, 0, SLOT, stream);
  hipMemsetAsync((char*)hbD + SLOT, 0xFF, 2*SLOT, stream);

  k_conv<<<3072,256,0,stream>>>(whh0f, whh0c, 786432);
  k_conv<<<3072,256,0,stream>>>(whh0b, whh0c+786432, 786432);
  k_conv_pad<<<576,256,0,stream>>>(wih0f, wih0c, 1536, 69, 96);
  k_conv_pad<<<576,256,0,stream>>>(wih0b, wih0c+1536*96, 1536, 69, 96);
  k_conv<<<6144,256,0,stream>>>(wih1f, wih1c, 1572864);
  k_conv<<<6144,256,0,stream>>>(wih1b, wih1c+1572864, 1572864);
  k_conv<<<3072,256,0,stream>>>(whh1f, whh1c, 786432);
  k_xpose<<<1024,64,0,stream>>>(x, xT);

  k_gru0<<<32,512,0,stream>>>(xT, whh0c, wih0c, bih0f,bhh0f,bih0b,bhh0b, l0out, hbB, 30000);
  k_gru1<<<64,256,0,stream>>>(l0out, wih1c, whh1c, bih1f,bhh1f,bih1b,bhh1b, l1cat, hbD, 30000);
  k_fc<<<3,256,0,stream>>>(l1cat, fcw, fcb, (float*)d_out);
}